// Round 1
// baseline (127.938 us; speedup 1.0000x reference)
//
#include <hip/hip_runtime.h>
#include <math.h>

typedef _Float16 f16;
typedef __attribute__((ext_vector_type(8))) _Float16 f16x8;
typedef __attribute__((ext_vector_type(4))) _Float16 f16x4;
typedef __attribute__((ext_vector_type(4))) float f32x4;

constexpr int BATCH = 32;
constexpr int QL = 1024;
constexpr int KL = 1024;
constexpr int D = 128;
constexpr int BQ = 64;    // query rows per block (16 per wave)
constexpr int BK = 64;    // key rows per tile
constexpr int DKP = 136;  // sK row pitch in halves (272 B, 16B-aligned rows)
constexpr int BKP = 72;   // sVT/sP row pitch in halves (144 B)

// scale * log2(e): softmax computed in exp2 domain
#define CSC 0.12752863187087177f

static __device__ __forceinline__ f16x4 pk4(float x, float y, float z, float w) {
  auto a = __builtin_amdgcn_cvt_pkrtz(x, y);
  auto b = __builtin_amdgcn_cvt_pkrtz(z, w);
  f16x4 h;
  h[0] = (f16)a[0]; h[1] = (f16)a[1]; h[2] = (f16)b[0]; h[3] = (f16)b[1];
  return h;
}
static __device__ __forceinline__ f16x8 pk8(float4 u, float4 v) {
  f16x4 a = pk4(u.x, u.y, u.z, u.w);
  f16x4 b = pk4(v.x, v.y, v.z, v.w);
  f16x8 h;
  h[0] = a[0]; h[1] = a[1]; h[2] = a[2]; h[3] = a[3];
  h[4] = b[0]; h[5] = b[1]; h[6] = b[2]; h[7] = b[3];
  return h;
}

// DPP lane move (VALU pipe — replaces ds_bpermute-based __shfl_xor)
template <int CTRL>
static __device__ __forceinline__ float dppf(float v) {
  int x = __float_as_int(v);
  x = __builtin_amdgcn_update_dpp(x, x, CTRL, 0xf, 0xf, false);
  return __int_as_float(x);
}
static __device__ __forceinline__ float rmax16(float v) {
  v = fmaxf(v, dppf<0xB1>(v));    // quad_perm [1,0,3,2]
  v = fmaxf(v, dppf<0x4E>(v));    // quad_perm [2,3,0,1]
  v = fmaxf(v, dppf<0x141>(v));   // row_half_mirror
  v = fmaxf(v, dppf<0x140>(v));   // row_mirror
  return v;
}
static __device__ __forceinline__ float rsum16(float v) {
  v += dppf<0xB1>(v);
  v += dppf<0x4E>(v);
  v += dppf<0x141>(v);
  v += dppf<0x140>(v);
  return v;
}

// ---- issue global loads for tile T of this block's batch into reg set (KR,VR)
#define ISSUE(KR, VR, T)                                                   \
  do {                                                                     \
    const float4* Kt = (const float4*)(Kb + (size_t)(T) * BK * D);         \
    _Pragma("unroll")                                                      \
    for (int i_ = 0; i_ < 4; ++i_) {                                       \
      int cc_ = tid + i_ * 256;                                            \
      int row_ = cc_ >> 4, d04_ = (cc_ & 15) * 2;                          \
      KR[2 * i_]     = Kt[row_ * 32 + d04_];                               \
      KR[2 * i_ + 1] = Kt[row_ * 32 + d04_ + 1];                           \
    }                                                                      \
    const float* Vt = Vb + (size_t)(T) * BK * D;                           \
    _Pragma("unroll")                                                      \
    for (int i_ = 0; i_ < 2; ++i_) {                                       \
      int f_ = tid + i_ * 256;                                             \
      const float* base_ = Vt + (size_t)((f_ & 15) * 4) * D + (f_ >> 4) * 4; \
      VR[i_ * 4 + 0] = *(const float4*)(base_);                            \
      VR[i_ * 4 + 1] = *(const float4*)(base_ + D);                        \
      VR[i_ * 4 + 2] = *(const float4*)(base_ + 2 * D);                    \
      VR[i_ * 4 + 3] = *(const float4*)(base_ + 3 * D);                    \
    }                                                                      \
  } while (0)

// ---- convert+store reg set (KR,VR) into LDS buffer NB (literal 0/1).
// Compiler inserts a COUNTED vmcnt here (the other set's 16 loads stay in
// flight) — this is the distance-2 pipeline payoff.
#define DRAIN(KR, VR, NB)                                                  \
  do {                                                                     \
    _Pragma("unroll")                                                      \
    for (int i_ = 0; i_ < 4; ++i_) {                                       \
      int cc_ = tid + i_ * 256;                                            \
      int row_ = cc_ >> 4, d0_ = (cc_ & 15) * 8;                           \
      int rp_ = (row_ & 3) * 16 + (row_ >> 2);                             \
      *(f16x8*)&sK[NB][rp_][d0_] = pk8(KR[2 * i_], KR[2 * i_ + 1]);        \
    }                                                                      \
    _Pragma("unroll")                                                      \
    for (int i_ = 0; i_ < 2; ++i_) {                                       \
      int f_ = tid + i_ * 256;                                             \
      int k0_ = (f_ & 15) * 4, d0_ = (f_ >> 4) * 4;                        \
      float4 r0_ = VR[i_*4+0], r1_ = VR[i_*4+1], r2_ = VR[i_*4+2], r3_ = VR[i_*4+3]; \
      *(f16x4*)&sVT[NB][d0_ + 0][k0_] = pk4(r0_.x, r1_.x, r2_.x, r3_.x);   \
      *(f16x4*)&sVT[NB][d0_ + 1][k0_] = pk4(r0_.y, r1_.y, r2_.y, r3_.y);   \
      *(f16x4*)&sVT[NB][d0_ + 2][k0_] = pk4(r0_.z, r1_.z, r2_.z, r3_.z);   \
      *(f16x4*)&sVT[NB][d0_ + 3][k0_] = pk4(r0_.w, r1_.w, r2_.w, r3_.w);   \
    }                                                                      \
  } while (0)

// ---- raw barrier: lgkmcnt(0) for cross-wave LDS visibility, but NO vmcnt
// drain — in-flight global prefetch survives the barrier (unlike
// __syncthreads(), which hipcc lowers with s_waitcnt vmcnt(0)).
#define TILE_BARRIER()                                                     \
  do {                                                                     \
    asm volatile("s_waitcnt lgkmcnt(0)" ::: "memory");                     \
    __builtin_amdgcn_s_barrier();                                          \
    asm volatile("" ::: "memory");                                         \
  } while (0)

// ---- one tile of S = QK^T -> online softmax -> O += P V, from buffer CB
#define COMPUTE(CB)                                                        \
  do {                                                                     \
    f32x4 sv[4];                                                           \
    _Pragma("unroll")                                                      \
    for (int ct = 0; ct < 4; ++ct) {                                       \
      f32x4 cacc = (f32x4){0.f, 0.f, 0.f, 0.f};                            \
      _Pragma("unroll")                                                    \
      for (int kc = 0; kc < 4; ++kc) {                                     \
        f16x8 kf = *(const f16x8*)&sK[CB][ct * 16 + l16][kc * 32 + quad * 8]; \
        cacc = __builtin_amdgcn_mfma_f32_16x16x32_f16(qfrag[kc], kf, cacc, 0, 0, 0); \
      }                                                                    \
      sv[ct] = cacc;                                                       \
    }                                                                      \
    /* scale into log2 domain + key-padding mask (kk = t*64 + l16*4 + ct) */ \
    _Pragma("unroll")                                                      \
    for (int ct = 0; ct < 4; ++ct) {                                       \
      bool ok = (t * BK + l16 * 4 + ct) < vl;                              \
      _Pragma("unroll")                                                    \
      for (int r = 0; r < 4; ++r)                                          \
        sv[ct][r] = ok ? sv[ct][r] * CSC : -1.0e9f;                        \
    }                                                                      \
    /* online softmax (DPP reductions — VALU pipe, no LDS) */              \
    float mnew[4], alpha[4];                                               \
    _Pragma("unroll")                                                      \
    for (int r = 0; r < 4; ++r) {                                          \
      float v = fmaxf(fmaxf(sv[0][r], sv[1][r]), fmaxf(sv[2][r], sv[3][r])); \
      v = rmax16(v);                                                       \
      mnew[r]  = fmaxf(m2[r], v);                                          \
      alpha[r] = __builtin_amdgcn_exp2f(m2[r] - mnew[r]);                  \
      m2[r]    = mnew[r];                                                  \
    }                                                                      \
    _Pragma("unroll")                                                      \
    for (int r = 0; r < 4; ++r) {                                          \
      float ls = 0.f;                                                      \
      _Pragma("unroll")                                                    \
      for (int ct = 0; ct < 4; ++ct) {                                     \
        float p = __builtin_amdgcn_exp2f(sv[ct][r] - mnew[r]);             \
        sv[ct][r] = p;                                                     \
        ls += p;                                                           \
      }                                                                    \
      lsum[r] = lsum[r] * alpha[r] + rsum16(ls);                           \
      *(f16x4*)&sP[wave][quad * 4 + r][l16 * 4] =                          \
          pk4(sv[0][r], sv[1][r], sv[2][r], sv[3][r]);                     \
      _Pragma("unroll")                                                    \
      for (int dt = 0; dt < 8; ++dt) o[dt][r] *= alpha[r];                 \
    }                                                                      \
    /* sP is wave-private: in-wave DS ordering + waitcnt suffices */       \
    asm volatile("s_waitcnt lgkmcnt(0)" ::: "memory");                     \
    _Pragma("unroll")                                                      \
    for (int ks = 0; ks < 2; ++ks) {                                       \
      f16x8 pf = *(const f16x8*)&sP[wave][l16][ks * 32 + quad * 8];        \
      _Pragma("unroll")                                                    \
      for (int dt = 0; dt < 8; ++dt) {                                     \
        f16x8 vf = *(const f16x8*)&sVT[CB][dt * 16 + l16][ks * 32 + quad * 8]; \
        o[dt] = __builtin_amdgcn_mfma_f32_16x16x32_f16(pf, vf, o[dt], 0, 0, 0); \
      }                                                                    \
    }                                                                      \
  } while (0)

__global__ __launch_bounds__(256, 2)
void attn_fwd(const float* __restrict__ Qp, const float* __restrict__ Kp,
              const float* __restrict__ Vp, const int* __restrict__ VLp,
              float* __restrict__ Op) {
  // double-buffered tiles: ONE barrier per K-tile (81 KB -> 2 blocks/CU)
  __shared__ f16 sK[2][BK][DKP];   // ROW-PERMUTED: pos p holds key (p&15)*4+(p>>4)
  __shared__ f16 sVT[2][D][BKP];   // V tile transposed [d][kk]
  __shared__ f16 sP[4][16][BKP];   // per-wave P tile [row][kk]
  __shared__ int sN[32];
  __shared__ int sI[32];           // cost-rank -> batch

  const int tid  = threadIdx.x;
  const int wave = tid >> 6, lane = tid & 63;
  const int l16  = lane & 15, quad = lane >> 4;

  // ---- XCD-bound, LPT-balanced static schedule.
  // Round-robin dispatch: XCD = id & 7; CU gets blocks id and id+256.
  // Each XCD owns 4 batches by cost-rank {x, 15-x, 16+x, 31-x} (bridge-deal:
  // per-XCD tile-work ~uniform for any valid_lens distribution), and ALL 16
  // qt-blocks of those batches -> per-XCD K/V working set ~2-4 MB, fits the
  // 4 MB XCD L2 (vs scattering each batch over 8 L2s = 2.4x HBM refetch).
  // Within an XCD: j=id>>3 in 0..63; jj=(j<32)?j:95-j pairs (j, j+32) as
  // (jj, 63-jj) -> CU pair = (rank-slot lr, 3-lr) = cheap+expensive: LPT.
  if (tid < 32) sN[tid] = (VLp[tid] + BK - 1) / BK;
  __syncthreads();
  if (tid < 32) {
    int nb = sN[tid], r = 0;
    #pragma unroll
    for (int k = 0; k < 32; ++k) {
      int nk = sN[k];
      r += (nk > nb) || (nk == nb && k < tid);
    }
    sI[r] = tid;  // invert: rank -> batch
  }
  __syncthreads();
  const int xcd = blockIdx.x & 7;
  const int j   = (int)blockIdx.x >> 3;        // 0..63 within XCD
  const int jj  = (j < 32) ? j : (95 - j);     // pair (j, j+32) -> (jj, 63-jj)
  const int lr  = jj >> 4;                     // local rank slot 0..3
  const int qt  = jj & 15;
  const int grank = (lr == 0) ? xcd : (lr == 1) ? (15 - xcd)
                  : (lr == 2) ? (16 + xcd) : (31 - xcd);
  const int b  = sI[grank];
  const int vl = VLp[b];

  const float* Kb = Kp + (size_t)b * KL * D;
  const float* Vb = Vp + (size_t)b * KL * D;
  const int ntiles = (vl + BK - 1) / BK;  // fully-masked tiles contribute exactly 0

  // ---- two staging reg sets: distance-2 prefetch pipeline
  float4 kA[8], vA[8], kB[8], vB[8];

  // Q loads FIRST (oldest in vmcnt order): converting qfrag then waits
  // vmcnt(32), leaving both K/V prefetch sets in flight.
  const float* Qb = Qp + ((size_t)(b * QL + qt * BQ + wave * 16 + l16)) * D;
  float4 qtmp[8];
  #pragma unroll
  for (int kc = 0; kc < 4; ++kc) {
    const float* p = Qb + kc * 32 + quad * 8;
    qtmp[2 * kc]     = *(const float4*)p;
    qtmp[2 * kc + 1] = *(const float4*)(p + 4);
  }

  ISSUE(kA, vA, 0);
  if (ntiles > 1) ISSUE(kB, vB, 1);

  f16x8 qfrag[4];
  #pragma unroll
  for (int kc = 0; kc < 4; ++kc) qfrag[kc] = pk8(qtmp[2 * kc], qtmp[2 * kc + 1]);

  float m2[4]   = {-INFINITY, -INFINITY, -INFINITY, -INFINITY};
  float lsum[4] = {0.f, 0.f, 0.f, 0.f};
  f32x4 o[8];
  #pragma unroll
  for (int dt = 0; dt < 8; ++dt) o[dt] = (f32x4){0.f, 0.f, 0.f, 0.f};

  // drain tile 0 (waits only its own 16 loads; tile 1's stay in flight)
  DRAIN(kA, vA, 0);
  TILE_BARRIER();

  // ---- main loop, 2 tiles per trip (static reg-set/buffer indices).
  // iter t: issue t+2 into the freed set, compute t, drain t+1 (issued a
  // full iteration ago -> counted vmcnt, near-zero stall), raw barrier.
  int t = 0;
  for (;;) {
    // even phase: buf0, issue->A, drain B
    if (t + 2 < ntiles) ISSUE(kA, vA, t + 2);
    COMPUTE(0);
    if (t + 1 >= ntiles) break;
    DRAIN(kB, vB, 1);
    TILE_BARRIER();
    ++t;
    // odd phase: buf1, issue->B, drain A
    if (t + 2 < ntiles) ISSUE(kB, vB, t + 2);
    COMPUTE(1);
    if (t + 1 >= ntiles) break;
    DRAIN(kA, vA, 0);
    TILE_BARRIER();
    ++t;
  }

  // ---- epilogue: O /= l, C-layout store (64B segments per 16 lanes)
  float* Ob = Op + ((size_t)(b * QL + qt * BQ + wave * 16)) * D;
  #pragma unroll
  for (int r = 0; r < 4; ++r) {
    float inv = 1.0f / lsum[r];
    int row = quad * 4 + r;
    #pragma unroll
    for (int dt = 0; dt < 8; ++dt)
      Ob[(size_t)row * D + dt * 16 + l16] = o[dt][r] * inv;
  }
}

extern "C" void kernel_launch(void* const* d_in, const int* in_sizes, int n_in,
                              void* d_out, int out_size, void* d_ws, size_t ws_size,
                              hipStream_t stream) {
  const float* Qp = (const float*)d_in[0];
  const float* Kp = (const float*)d_in[1];
  const float* Vp = (const float*)d_in[2];
  const int*   VL = (const int*)d_in[3];
  float* Op = (float*)d_out;

  attn_fwd<<<dim3(QL / BQ * BATCH), dim3(256), 0, stream>>>(Qp, Kp, Vp, VL, Op);
}

// Round 3
// 116.285 us; speedup vs baseline: 1.1002x; 1.1002x over previous
//
#include <hip/hip_runtime.h>
#include <math.h>

typedef _Float16 f16;
typedef __attribute__((ext_vector_type(8))) _Float16 f16x8;
typedef __attribute__((ext_vector_type(4))) _Float16 f16x4;
typedef __attribute__((ext_vector_type(4))) float f32x4;

constexpr int BATCH = 32;
constexpr int QL = 1024;
constexpr int KL = 1024;
constexpr int D = 128;
constexpr int BQ = 64;    // query rows per block (16 per wave)
constexpr int BK = 64;    // key rows per tile
constexpr int DKP = 136;  // sK row pitch in halves (272 B, 16B-aligned rows)
constexpr int BKP = 72;   // sVT/sP row pitch in halves (144 B)

// scale * log2(e): softmax computed in exp2 domain
#define CSC 0.12752863187087177f

static __device__ __forceinline__ f16x4 pk4(float x, float y, float z, float w) {
  auto a = __builtin_amdgcn_cvt_pkrtz(x, y);
  auto b = __builtin_amdgcn_cvt_pkrtz(z, w);
  f16x4 h;
  h[0] = (f16)a[0]; h[1] = (f16)a[1]; h[2] = (f16)b[0]; h[3] = (f16)b[1];
  return h;
}
static __device__ __forceinline__ f16x8 pk8(float4 u, float4 v) {
  f16x4 a = pk4(u.x, u.y, u.z, u.w);
  f16x4 b = pk4(v.x, v.y, v.z, v.w);
  f16x8 h;
  h[0] = a[0]; h[1] = a[1]; h[2] = a[2]; h[3] = a[3];
  h[4] = b[0]; h[5] = b[1]; h[6] = b[2]; h[7] = b[3];
  return h;
}

// DPP lane move (VALU pipe — replaces ds_bpermute-based __shfl_xor)
template <int CTRL>
static __device__ __forceinline__ float dppf(float v) {
  int x = __float_as_int(v);
  x = __builtin_amdgcn_update_dpp(x, x, CTRL, 0xf, 0xf, false);
  return __int_as_float(x);
}
static __device__ __forceinline__ float rmax16(float v) {
  v = fmaxf(v, dppf<0xB1>(v));    // quad_perm [1,0,3,2]
  v = fmaxf(v, dppf<0x4E>(v));    // quad_perm [2,3,0,1]
  v = fmaxf(v, dppf<0x141>(v));   // row_half_mirror
  v = fmaxf(v, dppf<0x140>(v));   // row_mirror
  return v;
}
static __device__ __forceinline__ float rsum16(float v) {
  v += dppf<0xB1>(v);
  v += dppf<0x4E>(v);
  v += dppf<0x141>(v);
  v += dppf<0x140>(v);
  return v;
}

__global__ __launch_bounds__(256, 2)
void attn_fwd(const float* __restrict__ Qp, const float* __restrict__ Kp,
              const float* __restrict__ Vp, const int* __restrict__ VLp,
              float* __restrict__ Op) {
  // double-buffered tiles: ONE barrier per K-tile (81 KB -> 2 blocks/CU)
  __shared__ f16 sK[2][BK][DKP];   // ROW-PERMUTED: pos p holds key (p&15)*4+(p>>4)
  __shared__ f16 sVT[2][D][BKP];   // V tile transposed [d][kk]
  __shared__ f16 sP[4][16][BKP];   // per-wave P tile [row][kk]
  __shared__ int sN[32];
  __shared__ int sI[32];           // cost-rank -> batch

  const int tid  = threadIdx.x;
  const int wave = tid >> 6, lane = tid & 63;
  const int l16  = lane & 15, quad = lane >> 4;

  // ---- XCD-bound, LPT-balanced static schedule (VERIFIED by R1: FETCH_SIZE
  // 81 MB -> 19 MB, so each XCD's 4 batches stay L2-resident).
  // Round-robin dispatch: XCD = id & 7; CU gets blocks id and id+256.
  // Each XCD owns 4 batches by cost-rank {x, 15-x, 16+x, 31-x}; all 16
  // qt-blocks of those batches land on that XCD. Within an XCD: j=id>>3;
  // jj=(j<32)?j:95-j pairs (j, j+32) as (jj, 63-jj) -> CU pair gets rank
  // slots (lr, 3-lr) = cheap+expensive: LPT-balanced.
  if (tid < 32) sN[tid] = (VLp[tid] + BK - 1) / BK;
  __syncthreads();
  if (tid < 32) {
    int nb = sN[tid], r = 0;
    #pragma unroll
    for (int k = 0; k < 32; ++k) {
      int nk = sN[k];
      r += (nk > nb) || (nk == nb && k < tid);
    }
    sI[r] = tid;  // invert: rank -> batch
  }
  __syncthreads();
  const int xcd = blockIdx.x & 7;
  const int j   = (int)blockIdx.x >> 3;        // 0..63 within XCD
  const int jj  = (j < 32) ? j : (95 - j);     // pair (j, j+32) -> (jj, 63-jj)
  const int lr  = jj >> 4;                     // local rank slot 0..3
  const int qt  = jj & 15;
  const int grank = (lr == 0) ? xcd : (lr == 1) ? (15 - xcd)
                  : (lr == 2) ? (16 + xcd) : (31 - xcd);
  const int b  = sI[grank];
  const int vl = VLp[b];

  const float* Kb = Kp + (size_t)b * KL * D;
  const float* Vb = Vp + (size_t)b * KL * D;
  const int ntiles = (vl + BK - 1) / BK;  // fully-masked tiles contribute exactly 0

  // ---- SINGLE staging reg set, distance-1 prefetch (R1 post-mortem: two
  // sets = 128 staging VGPRs -> scratch spills, WRITE_SIZE +3.8 MB, -15%.
  // With XCD-bound L2-resident K/V (~200-400 cyc), one compute phase covers
  // the load latency, so distance-1 is sufficient and spill-free.)
  float4 kreg[8], vreg[8];

  // Q loads first (oldest in vmcnt order): qfrag conversion then leaves the
  // tile-0 K/V loads still in flight.
  const float* Qb = Qp + ((size_t)(b * QL + qt * BQ + wave * 16 + l16)) * D;
  float4 qtmp[8];
  #pragma unroll
  for (int kc = 0; kc < 4; ++kc) {
    const float* p = Qb + kc * 32 + quad * 8;
    qtmp[2 * kc]     = *(const float4*)p;
    qtmp[2 * kc + 1] = *(const float4*)(p + 4);
  }

  // ---- issue tile-0 loads
  {
    const float4* Kt = (const float4*)Kb;
    #pragma unroll
    for (int i = 0; i < 4; ++i) {
      int cc = tid + i * 256;
      int row = cc >> 4, d04 = (cc & 15) * 2;
      kreg[2 * i]     = Kt[row * 32 + d04];
      kreg[2 * i + 1] = Kt[row * 32 + d04 + 1];
    }
    #pragma unroll
    for (int i = 0; i < 2; ++i) {
      int f = tid + i * 256;
      const float* base = Vb + (size_t)((f & 15) * 4) * D + (f >> 4) * 4;
      vreg[i * 4 + 0] = *(const float4*)(base);
      vreg[i * 4 + 1] = *(const float4*)(base + D);
      vreg[i * 4 + 2] = *(const float4*)(base + 2 * D);
      vreg[i * 4 + 3] = *(const float4*)(base + 3 * D);
    }
  }

  f16x8 qfrag[4];
  #pragma unroll
  for (int kc = 0; kc < 4; ++kc) qfrag[kc] = pk8(qtmp[2 * kc], qtmp[2 * kc + 1]);

  float m2[4]   = {-INFINITY, -INFINITY, -INFINITY, -INFINITY};
  float lsum[4] = {0.f, 0.f, 0.f, 0.f};
  f32x4 o[8];
  #pragma unroll
  for (int dt = 0; dt < 8; ++dt) o[dt] = (f32x4){0.f, 0.f, 0.f, 0.f};

  // ---- drain tile 0 into buffer 0
  #pragma unroll
  for (int i = 0; i < 4; ++i) {
    int cc = tid + i * 256;
    int row = cc >> 4, d0 = (cc & 15) * 8;
    int rp = (row & 3) * 16 + (row >> 2);
    *(f16x8*)&sK[0][rp][d0] = pk8(kreg[2 * i], kreg[2 * i + 1]);
  }
  #pragma unroll
  for (int i = 0; i < 2; ++i) {
    int f = tid + i * 256;
    int k0 = (f & 15) * 4, d0 = (f >> 4) * 4;
    float4 r0 = vreg[i*4+0], r1 = vreg[i*4+1], r2 = vreg[i*4+2], r3 = vreg[i*4+3];
    *(f16x4*)&sVT[0][d0 + 0][k0] = pk4(r0.x, r1.x, r2.x, r3.x);
    *(f16x4*)&sVT[0][d0 + 1][k0] = pk4(r0.y, r1.y, r2.y, r3.y);
    *(f16x4*)&sVT[0][d0 + 2][k0] = pk4(r0.z, r1.z, r2.z, r3.z);
    *(f16x4*)&sVT[0][d0 + 3][k0] = pk4(r0.w, r1.w, r2.w, r3.w);
  }
  // raw barrier: lgkmcnt for LDS visibility, but NO forced vmcnt(0) drain
  // (unlike __syncthreads) — any still-inflight prefetch survives.
  asm volatile("s_waitcnt lgkmcnt(0)" ::: "memory");
  __builtin_amdgcn_s_barrier();
  asm volatile("" ::: "memory");

  for (int t = 0; t < ntiles; ++t) {
    const int cur = t & 1, nxt = cur ^ 1;
    const bool more = (t + 1 < ntiles);

    // ---- issue global loads for tile t+1 (await only in the drain, after
    // the full compute phase -> L2 latency fully covered)
    if (more) {
      const float4* Kt = (const float4*)(Kb + (size_t)(t + 1) * BK * D);
      #pragma unroll
      for (int i = 0; i < 4; ++i) {
        int cc = tid + i * 256;
        int row = cc >> 4, d04 = (cc & 15) * 2;
        kreg[2 * i]     = Kt[row * 32 + d04];
        kreg[2 * i + 1] = Kt[row * 32 + d04 + 1];
      }
      const float* Vt = Vb + (size_t)(t + 1) * BK * D;
      #pragma unroll
      for (int i = 0; i < 2; ++i) {
        int f = tid + i * 256;
        const float* base = Vt + (size_t)((f & 15) * 4) * D + (f >> 4) * 4;
        vreg[i * 4 + 0] = *(const float4*)(base);
        vreg[i * 4 + 1] = *(const float4*)(base + D);
        vreg[i * 4 + 2] = *(const float4*)(base + 2 * D);
        vreg[i * 4 + 3] = *(const float4*)(base + 3 * D);
      }
    }

    // ---- S = Q K^T : 4 ct x 4 kc MFMA
    // LDS row ct*16+l16 holds actual key kk = l16*4 + ct (permuted staging)
    f32x4 sv[4];
    #pragma unroll
    for (int ct = 0; ct < 4; ++ct) {
      f32x4 cacc = (f32x4){0.f, 0.f, 0.f, 0.f};
      #pragma unroll
      for (int kc = 0; kc < 4; ++kc) {
        f16x8 kf = *(const f16x8*)&sK[cur][ct * 16 + l16][kc * 32 + quad * 8];
        cacc = __builtin_amdgcn_mfma_f32_16x16x32_f16(qfrag[kc], kf, cacc, 0, 0, 0);
      }
      sv[ct] = cacc;
    }

    // ---- scale into log2 domain + key-padding mask (kk = t*64 + l16*4 + ct)
    #pragma unroll
    for (int ct = 0; ct < 4; ++ct) {
      bool ok = (t * BK + l16 * 4 + ct) < vl;
      #pragma unroll
      for (int r = 0; r < 4; ++r)
        sv[ct][r] = ok ? sv[ct][r] * CSC : -1.0e9f;
    }

    // ---- online softmax (DPP reductions — VALU pipe, no LDS)
    float mnew[4], alpha[4];
    #pragma unroll
    for (int r = 0; r < 4; ++r) {
      float v = fmaxf(fmaxf(sv[0][r], sv[1][r]), fmaxf(sv[2][r], sv[3][r]));
      v = rmax16(v);
      mnew[r]  = fmaxf(m2[r], v);
      alpha[r] = __builtin_amdgcn_exp2f(m2[r] - mnew[r]);
      m2[r]    = mnew[r];
    }
    #pragma unroll
    for (int r = 0; r < 4; ++r) {
      float ls = 0.f;
      #pragma unroll
      for (int ct = 0; ct < 4; ++ct) {
        float p = __builtin_amdgcn_exp2f(sv[ct][r] - mnew[r]);
        sv[ct][r] = p;
        ls += p;
      }
      lsum[r] = lsum[r] * alpha[r] + rsum16(ls);
      // P -> LDS: lane's 4 ct-values are kk-contiguous (l16*4+ct) -> b64
      *(f16x4*)&sP[wave][quad * 4 + r][l16 * 4] =
          pk4(sv[0][r], sv[1][r], sv[2][r], sv[3][r]);
      #pragma unroll
      for (int dt = 0; dt < 8; ++dt) o[dt][r] *= alpha[r];
    }

    // sP is wave-private: in-wave DS ordering + waitcnt suffices (no barrier)
    asm volatile("s_waitcnt lgkmcnt(0)" ::: "memory");

    // ---- O += P V
    #pragma unroll
    for (int ks = 0; ks < 2; ++ks) {
      f16x8 pf = *(const f16x8*)&sP[wave][l16][ks * 32 + quad * 8];
      #pragma unroll
      for (int dt = 0; dt < 8; ++dt) {
        f16x8 vf = *(const f16x8*)&sVT[cur][dt * 16 + l16][ks * 32 + quad * 8];
        o[dt] = __builtin_amdgcn_mfma_f32_16x16x32_f16(pf, vf, o[dt], 0, 0, 0);
      }
    }

    // ---- drain prefetch regs into the other buffer (counted vmcnt here —
    // loads were issued a full compute phase ago)
    if (more) {
      #pragma unroll
      for (int i = 0; i < 4; ++i) {
        int cc = tid + i * 256;
        int row = cc >> 4, d0 = (cc & 15) * 8;
        int rp = (row & 3) * 16 + (row >> 2);
        *(f16x8*)&sK[nxt][rp][d0] = pk8(kreg[2 * i], kreg[2 * i + 1]);
      }
      #pragma unroll
      for (int i = 0; i < 2; ++i) {
        int f = tid + i * 256;
        int k0 = (f & 15) * 4, d0 = (f >> 4) * 4;
        float4 r0 = vreg[i*4+0], r1 = vreg[i*4+1], r2 = vreg[i*4+2], r3 = vreg[i*4+3];
        *(f16x4*)&sVT[nxt][d0 + 0][k0] = pk4(r0.x, r1.x, r2.x, r3.x);
        *(f16x4*)&sVT[nxt][d0 + 1][k0] = pk4(r0.y, r1.y, r2.y, r3.y);
        *(f16x4*)&sVT[nxt][d0 + 2][k0] = pk4(r0.z, r1.z, r2.z, r3.z);
        *(f16x4*)&sVT[nxt][d0 + 3][k0] = pk4(r0.w, r1.w, r2.w, r3.w);
      }
    }
    // raw barrier (no vmcnt drain; nothing in flight to hide anyway after
    // the drain, but __syncthreads' expcnt/vmcnt(0) is pure overhead)
    asm volatile("s_waitcnt lgkmcnt(0)" ::: "memory");
    __builtin_amdgcn_s_barrier();
    asm volatile("" ::: "memory");
  }

  // ---- epilogue: O /= l, C-layout store (64B segments per 16 lanes)
  float* Ob = Op + ((size_t)(b * QL + qt * BQ + wave * 16)) * D;
  #pragma unroll
  for (int r = 0; r < 4; ++r) {
    float inv = 1.0f / lsum[r];
    int row = quad * 4 + r;
    #pragma unroll
    for (int dt = 0; dt < 8; ++dt)
      Ob[(size_t)row * D + dt * 16 + l16] = o[dt][r] * inv;
  }
}

extern "C" void kernel_launch(void* const* d_in, const int* in_sizes, int n_in,
                              void* d_out, int out_size, void* d_ws, size_t ws_size,
                              hipStream_t stream) {
  const float* Qp = (const float*)d_in[0];
  const float* Kp = (const float*)d_in[1];
  const float* Vp = (const float*)d_in[2];
  const int*   VL = (const int*)d_in[3];
  float* Op = (float*)d_out;

  attn_fwd<<<dim3(QL / BQ * BATCH), dim3(256), 0, stream>>>(Qp, Kp, Vp, VL, Op);
}